// Round 7
// baseline (221.378 us; speedup 1.0000x reference)
//
#include <hip/hip_runtime.h>
#include <hip/hip_bf16.h>

// SelfAttention B=2,N=4096,E=512,H=8,D=64 — Round 17 (= R16 resubmit after
// infra failure; kernel re-audited for hangs: barrier counts uniform, LDS
// re-tile aliasing safe after vmcnt(0)+syncthreads, 64KB LDS cap respected).
// R15 matched (attn 82.7us). Non-attn stuck at ~138us; floor arithmetic says
// ~40us -> suspect GEMM epilogue scatter stores (~1M x 32B C-stores + 1M x 8B
// Vt-stores = partial-line L2 RMW storm). R16/17 rewrites both GEMM epilogues:
//  - C-blocks: SWAPPED mfma(b,a) -> lane holds 1 row x 4 consecutive cols ->
//    b64 LDS write into row-major 128x128 bf16 tile (8B-chunk XOR swizzle),
//    barrier, re-read rows -> 16B coalesced global stores.
//  - V-blocks (n0>=1024, block-uniform): classic mfma -> lane holds 4 seq x 1 d
//    -> b64 write into [d][seq] LDS tile -> coalesced Vt stores (256B runs).
// LDS tile aliases the dead double-buffer. attn/prep/ln unchanged.

#define ROWS 8192
#define EMB  512
#define SEQ  4096
#define HEADS 8
#define HD   64
#define QSCALE 0.18033688011112042f   // 0.125 * log2(e)

typedef __attribute__((ext_vector_type(8))) short bf16x8;
typedef __attribute__((ext_vector_type(4))) short bf16x4;
typedef __attribute__((ext_vector_type(4))) float f32x4;

__device__ __forceinline__ float bf16_to_f(unsigned short u) {
    union { unsigned int i; float f; } v; v.i = ((unsigned int)u) << 16; return v.f;
}
__device__ __forceinline__ unsigned short f_to_bf16(float f) {
    union { __hip_bfloat16 h; unsigned short u; } v; v.h = __float2bfloat16(f); return v.u;
}
// low16 = hi16(a), high16 = hi16(b) — single v_perm_b32
__device__ __forceinline__ unsigned int pack_bf16_trunc(float a, float b) {
    return __builtin_amdgcn_perm(__float_as_uint(b), __float_as_uint(a), 0x07060302u);
}
__device__ __forceinline__ void load_lds16(const void* g, void* l) {
    __builtin_amdgcn_global_load_lds(
        (const __attribute__((address_space(1))) void*)g,
        (__attribute__((address_space(3))) void*)l, 16, 0, 0);
}

// ---- inline dtype detection: fp32 buffers have wild "exponents" in halfwords.
__device__ __forceinline__ int detect_fp32(const void* x) {
    const unsigned short* p = (const unsigned short*)x;
    int t = threadIdx.x & 63;
    int cnt = 0;
    #pragma unroll
    for (int i = 0; i < 4; ++i) {
        unsigned short u = p[t * 4 + i];
        int e = (u >> 7) & 0xFF;
        cnt += (e >= 140) ? 1 : 0;
    }
    #pragma unroll
    for (int off = 32; off > 0; off >>= 1) cnt += __shfl_xor(cnt, off, 64);
    return cnt > 16;
}

// ---- fused prep: [0,4096) conv_x | [4096,4352) conv_wt | [4352,4364) conv_small
__global__ __launch_bounds__(256) void prep_kernel(
        const void* __restrict__ x, unsigned short* __restrict__ xb,
        const void* W0, const void* W1, const void* W2, const void* W3,
        unsigned short* __restrict__ Wt,
        const void* b0, const void* b1, const void* b2, const void* b3,
        const void* b4, const void* b5, float* __restrict__ bias_all) {
    int fp32 = detect_fp32(x);
    int bid = blockIdx.x;
    int tid = threadIdx.x;
    if (bid < 4096) {                       // ---- conv_x: x -> xb (bf16)
        if (!fp32) return;
        int i = (bid * 256 + tid) * 4;
        float4 v = *(const float4*)((const float*)x + i);
        ushort4 u = { f_to_bf16(v.x), f_to_bf16(v.y), f_to_bf16(v.z), f_to_bf16(v.w) };
        *(ushort4*)(xb + i) = u;
    } else if (bid < 4352) {                // ---- conv_wt: W[K][N] -> Wt[n][k]
        __shared__ float T[64][65];
        int idx0 = bid - 4096;
        int kt = idx0 & 7, nt = (idx0 >> 3) & 7, mat = idx0 >> 6;
        const void* src = (mat == 0) ? W0 : (mat == 1) ? W1 : (mat == 2) ? W2 : W3;
        for (int ii = 0; ii < 4; ++ii) {
            int idx = tid + ii * 256;
            int i = idx >> 4, j = (idx & 15) * 4;
            size_t g = (size_t)(kt * 64 + i) * 512 + nt * 64 + j;
            if (fp32) {
                float4 v = *(const float4*)((const float*)src + g);
                T[i][j] = v.x; T[i][j+1] = v.y; T[i][j+2] = v.z; T[i][j+3] = v.w;
            } else {
                ushort4 u = *(const ushort4*)((const unsigned short*)src + g);
                T[i][j] = bf16_to_f(u.x); T[i][j+1] = bf16_to_f(u.y);
                T[i][j+2] = bf16_to_f(u.z); T[i][j+3] = bf16_to_f(u.w);
            }
        }
        __syncthreads();
        for (int ii = 0; ii < 2; ++ii) {
            int idx = tid + ii * 256;
            int j = idx >> 3, ch = idx & 7;
            unsigned short pk[8];
            for (int t = 0; t < 8; ++t) pk[t] = f_to_bf16(T[ch * 8 + t][j]);
            *(bf16x8*)&Wt[(size_t)(mat * 512 + nt * 64 + j) * 512 + kt * 64 + ch * 8] = *(bf16x8*)pk;
        }
    } else {                                // ---- conv_small: 6 vecs -> bias_all
        int idx = (bid - 4352) * 256 + tid;
        int mat = idx >> 9, off = idx & 511;
        const void* src = (mat == 0) ? b0 : (mat == 1) ? b1 : (mat == 2) ? b2 :
                          (mat == 3) ? b3 : (mat == 4) ? b4 : b5;
        float v;
        if (fp32) v = ((const float*)src)[off];
        else      v = bf16_to_f(((const unsigned short*)src)[off]);
        bias_all[idx] = v;
    }
}

// ---- MFMA GEMM: C = A * Bt^T + bias, 128x128x64 tiles, 2-phase double-buffered.
// Epilogue: LDS re-tile (aliases dead dbuf) -> fully coalesced stores.
// C-blocks use swapped mfma(b,a); V-blocks (VtOut && n0>=1024) classic order.
template <typename OutT>
__global__ __launch_bounds__(256) void gemm_mfma_kernel(
        const unsigned short* __restrict__ A_conv, const unsigned short* __restrict__ A_raw,
        const unsigned short* __restrict__ Bt,
        const float* __restrict__ bias, OutT* __restrict__ C, int ldc, int scale_cols,
        unsigned short* __restrict__ VtOut) {
    __shared__ __align__(16) unsigned short smemg[2][2][128 * 64];  // [buf][A/B] 64KB
    const unsigned short* A = detect_fp32(A_raw) ? A_conv : A_raw;
    int tid = threadIdx.x;
    int wave = tid >> 6, lane = tid & 63;
    int l15 = lane & 15, quad = lane >> 4;

    int lin = blockIdx.x + gridDim.x * blockIdx.y;
    int nwg = gridDim.x * gridDim.y;
    int bx, by;
    if (nwg & 7) { bx = blockIdx.x; by = blockIdx.y; }
    else {
        int t = (lin & 7) * (nwg >> 3) + (lin >> 3);
        bx = t % gridDim.x; by = t / gridDim.x;
    }
    int m0 = by * 128, n0 = bx * 128;
    int wm = (wave & 1) * 64, wn = (wave >> 1) * 64;
    bool is_v = (VtOut != nullptr) && (n0 >= 1024);

    int rt = wave * 32 + (lane >> 3);
    int ch = (lane & 7) ^ ((lane >> 3) & 7);
    const unsigned short* ag = A  + (size_t)(m0 + rt) * 512 + ch * 8;
    const unsigned short* bg = Bt + (size_t)(n0 + rt) * 512 + ch * 8;

    f32x4 acc[4][4];
    for (int i = 0; i < 4; ++i) for (int j = 0; j < 4; ++j) acc[i][j] = (f32x4){0.f,0.f,0.f,0.f};

#define GSTAGE(buf, k0) do {                                                      \
        unsigned short* Atb = &smemg[buf][0][0];                                  \
        unsigned short* Bsb = &smemg[buf][1][0];                                  \
        _Pragma("unroll")                                                         \
        for (int j = 0; j < 4; ++j) {                                             \
            load_lds16(ag + (size_t)(j * 8) * 512 + (k0), &Atb[(wave * 32 + j * 8) * 64]); \
            load_lds16(bg + (size_t)(j * 8) * 512 + (k0), &Bsb[(wave * 32 + j * 8) * 64]); \
        }                                                                         \
    } while (0)

    GSTAGE(0, 0);   // prologue

    for (int s = 0; s < 8; ++s) {
        int cur = s & 1;
        asm volatile("s_waitcnt vmcnt(0)" ::: "memory");
        __builtin_amdgcn_sched_barrier(0);
        asm volatile("s_barrier" ::: "memory");
        __builtin_amdgcn_sched_barrier(0);
        if (s + 1 < 8) GSTAGE(cur ^ 1, (s + 1) * 64);   // in flight during compute

        const unsigned short* At = &smemg[cur][0][0];
        const unsigned short* Bs = &smemg[cur][1][0];
        #pragma unroll
        for (int ks = 0; ks < 2; ++ks) {
            bf16x8 a[4], b[4];
            #pragma unroll
            for (int f = 0; f < 4; ++f) {
                int pc = ((ks * 4 + quad) ^ (l15 & 7)) * 8;
                a[f] = *(const bf16x8*)&At[(wm + f * 16 + l15) * 64 + pc];
                b[f] = *(const bf16x8*)&Bs[(wn + f * 16 + l15) * 64 + pc];
            }
            if (is_v) {
                #pragma unroll
                for (int fm = 0; fm < 4; ++fm)
                    #pragma unroll
                    for (int fn = 0; fn < 4; ++fn)
                        acc[fm][fn] = __builtin_amdgcn_mfma_f32_16x16x32_bf16(a[fm], b[fn], acc[fm][fn], 0, 0, 0);
            } else {
                // swapped: intrinsic M-dim <- B rows (C's n), N-dim <- A rows (C's m)
                #pragma unroll
                for (int fm = 0; fm < 4; ++fm)
                    #pragma unroll
                    for (int fn = 0; fn < 4; ++fn)
                        acc[fm][fn] = __builtin_amdgcn_mfma_f32_16x16x32_bf16(b[fn], a[fm], acc[fm][fn], 0, 0, 0);
            }
        }
        __builtin_amdgcn_sched_barrier(0);
    }
#undef GSTAGE

    // ---- epilogue: LDS re-tile (32KB, aliases dbuf) -> coalesced stores
    __syncthreads();   // all waves done reading smemg
    unsigned short* LT = &smemg[0][0][0];   // [128 rows][128 ushorts], 8B-chunk swizzle

    float sc = (n0 < scale_cols) ? QSCALE : 1.f;   // 512-boundary is block-aligned

    if (is_v) {
        // classic acc: seq = wm+fm*16+quad*4+r, dcol = wn+fn*16+l15
        #pragma unroll
        for (int fm = 0; fm < 4; ++fm) {
            #pragma unroll
            for (int fn = 0; fn < 4; ++fn) {
                int dcol = wn + fn * 16 + l15;
                float bia = bias[n0 + dcol];
                int seq0 = wm + fm * 16 + quad * 4;
                ushort4 pk = { f_to_bf16(acc[fm][fn][0] + bia),
                               f_to_bf16(acc[fm][fn][1] + bia),
                               f_to_bf16(acc[fm][fn][2] + bia),
                               f_to_bf16(acc[fm][fn][3] + bia) };
                int c8 = (seq0 >> 2) ^ (dcol & 31);
                *(ushort4*)&LT[dcol * 128 + c8 * 4] = pk;
            }
        }
    } else {
        // swapped acc: row = wm+fm*16+l15, cols = wn+fn*16+quad*4+{0..3}
        #pragma unroll
        for (int fm = 0; fm < 4; ++fm) {
            #pragma unroll
            for (int fn = 0; fn < 4; ++fn) {
                int row = wm + fm * 16 + l15;
                int col0 = wn + fn * 16 + quad * 4;
                float4 b4 = *(const float4*)&bias[n0 + col0];
                ushort4 pk = { f_to_bf16((acc[fm][fn][0] + b4.x) * sc),
                               f_to_bf16((acc[fm][fn][1] + b4.y) * sc),
                               f_to_bf16((acc[fm][fn][2] + b4.z) * sc),
                               f_to_bf16((acc[fm][fn][3] + b4.w) * sc) };
                int c8 = (col0 >> 2) ^ (row & 31);
                *(ushort4*)&LT[row * 128 + c8 * 4] = pk;
            }
        }
    }
    __syncthreads();
    #pragma unroll
    for (int i = 0; i < 16; ++i) {
        int row = wave * 32 + i * 2 + (lane >> 5);
        int c8 = lane & 31;
        int phys = c8 ^ (row & 31);
        ushort4 v4 = *(const ushort4*)&LT[row * 128 + phys * 4];
        if (is_v) {
            int hd = n0 - 1024 + row;                     // d-channel 0..511
            int bh = (m0 >> 12) * 8 + (hd >> 6);
            int d  = hd & 63;
            *(ushort4*)&VtOut[((size_t)(bh * 64 + d)) * SEQ + (m0 & 4095) + c8 * 4] = v4;
        } else {
            *(ushort4*)&C[(size_t)(m0 + row) * ldc + n0 + c8 * 4] = v4;
        }
    }
}

// ---- MFMA flash attention, 2-phase double-buffered, K32 PV (R15, unchanged).
__global__ __launch_bounds__(256, 4) void attn_kernel(
        const unsigned short* __restrict__ QKV, const unsigned short* __restrict__ Vt,
        unsigned short* __restrict__ Ab) {
    __shared__ __align__(16) unsigned char smem[32768];
    float* Ored = (float*)smem;                 // epilogue [4 w][16 q][64 d] (16KB)
    float* Lred = (float*)(smem + 16384);       // epilogue [4 w][2 t][16 q] (512B)

    int tid = threadIdx.x;
    int wave = tid >> 6, lane = tid & 63;
    int l15 = lane & 15, quad = lane >> 4;
    int qh = wave >> 1, kh = wave & 1;
    int lin = blockIdx.x;
    int xcd = lin & 7, slot = lin >> 3;
    int grp = xcd + 8 * (slot >> 6);      // 16 (b,h) groups, 2 per XCD
    int qt = slot & 63;
    int h = grp & 7, b = grp >> 3;
    int bh = b * HEADS + h;
    size_t qrow0 = (size_t)b * SEQ + qt * 64;

    bf16x8 aq[2][2];
    #pragma unroll
    for (int t = 0; t < 2; ++t) {
        const unsigned short* qp = &QKV[(qrow0 + qh * 32 + t * 16 + l15) * 1536 + h * 64];
        aq[t][0] = *(const bf16x8*)&qp[quad * 8];
        aq[t][1] = *(const bf16x8*)&qp[32 + quad * 8];
    }
    f32x4 o[2][4];
    #pragma unroll
    for (int t = 0; t < 2; ++t)
        #pragma unroll
        for (int db = 0; db < 4; ++db) o[t][db] = (f32x4){0.f, 0.f, 0.f, 0.f};
    float lp[2] = {0.f, 0.f};

    int r8 = lane >> 3;
    int kch = (lane & 7) ^ (r8 & 7);
    int r0 = wave * 16 + r8;
    int r1 = wave * 16 + 8 + r8;
    int p0r = (r0 & 32) | (((r0 >> 2) & 3) << 3) | (((r0 >> 4) & 1) << 2) | (r0 & 3);
    int p1r = (r1 & 32) | (((r1 >> 2) & 3) << 3) | (((r1 >> 4) & 1) << 2) | (r1 & 3);
    const unsigned short* kg0 = &QKV[((size_t)b * SEQ + p0r) * 1536 + 512 + h * 64 + kch * 8];
    const unsigned short* kg1 = &QKV[((size_t)b * SEQ + p1r) * 1536 + 512 + h * 64 + kch * 8];
    const unsigned short* vg = &Vt[((size_t)bh * 64 + wave * 16 + r8) * SEQ + kch * 8];

#define STAGE(buf, kt2) do {                                                          \
        unsigned short* Ksb = (unsigned short*)(smem + (buf) * 8192);                 \
        unsigned short* Vsb = (unsigned short*)(smem + 16384 + (buf) * 8192);         \
        load_lds16(kg0 + (size_t)((kt2) * 64) * 1536, &Ksb[(wave * 16) * 64]);        \
        load_lds16(kg1 + (size_t)((kt2) * 64) * 1536, &Ksb[(wave * 16 + 8) * 64]);    \
        load_lds16(vg + (size_t)((kt2) * 64), &Vsb[(wave * 16) * 64]);                \
        load_lds16(vg + (size_t)((kt2) * 64) + (size_t)8 * SEQ,                       \
                   &Vsb[(wave * 16 + 8) * 64]);                                       \
    } while (0)

    STAGE(0, 0);   // prologue

    for (int kt = 0; kt < SEQ / 64; ++kt) {
        int cur = kt & 1;
        asm volatile("s_waitcnt vmcnt(0)" ::: "memory");
        __builtin_amdgcn_sched_barrier(0);
        asm volatile("s_barrier" ::: "memory");
        __builtin_amdgcn_sched_barrier(0);
        if (kt + 1 < SEQ / 64) STAGE(cur ^ 1, kt + 1);

        const unsigned short* Ksc = (const unsigned short*)(smem + cur * 8192);
        const unsigned short* Vsc = (const unsigned short*)(smem + 16384 + cur * 8192);

        bf16x8 kA[2][2];
        #pragma unroll
        for (int nb = 0; nb < 2; ++nb) {
            int krow = kh * 32 + nb * 16 + l15;
            int key = krow & 7;
            kA[nb][0] = *(const bf16x8*)&Ksc[krow * 64 + (quad ^ key) * 8];
            kA[nb][1] = *(const bf16x8*)&Ksc[krow * 64 + ((4 + quad) ^ key) * 8];
        }
        bf16x8 bv8[4];
        #pragma unroll
        for (int db = 0; db < 4; ++db) {
            int d = db * 16 + l15;
            bv8[db] = *(const bf16x8*)&Vsc[d * 64 + (((kh * 4 + quad) ^ (d & 7))) * 8];
        }
        #pragma unroll
        for (int t = 0; t < 2; ++t) {
            f32x4 sv0 = {0.f, 0.f, 0.f, 0.f};
            f32x4 sv1 = {0.f, 0.f, 0.f, 0.f};
            __builtin_amdgcn_s_setprio(1);
            sv0 = __builtin_amdgcn_mfma_f32_16x16x32_bf16(kA[0][0], aq[t][0], sv0, 0, 0, 0);
            sv0 = __builtin_amdgcn_mfma_f32_16x16x32_bf16(kA[0][1], aq[t][1], sv0, 0, 0, 0);
            sv1 = __builtin_amdgcn_mfma_f32_16x16x32_bf16(kA[1][0], aq[t][0], sv1, 0, 0, 0);
            sv1 = __builtin_amdgcn_mfma_f32_16x16x32_bf16(kA[1][1], aq[t][1], sv1, 0, 0, 0);
            __builtin_amdgcn_s_setprio(0);
            float p0 = __builtin_amdgcn_exp2f(sv0[0]);
            float p1 = __builtin_amdgcn_exp2f(sv0[1]);
            float p2 = __builtin_amdgcn_exp2f(sv0[2]);
            float p3 = __builtin_amdgcn_exp2f(sv0[3]);
            float p4 = __builtin_amdgcn_exp2f(sv1[0]);
            float p5 = __builtin_amdgcn_exp2f(sv1[1]);
            float p6 = __builtin_amdgcn_exp2f(sv1[2]);
            float p7 = __builtin_amdgcn_exp2f(sv1[3]);
            lp[t] += ((p0 + p1) + (p2 + p3)) + ((p4 + p5) + (p6 + p7));
            union { unsigned int u[4]; bf16x8 v; } ap;
            ap.u[0] = pack_bf16_trunc(p0, p1);
            ap.u[1] = pack_bf16_trunc(p2, p3);
            ap.u[2] = pack_bf16_trunc(p4, p5);
            ap.u[3] = pack_bf16_trunc(p6, p7);
            __builtin_amdgcn_s_setprio(1);
            #pragma unroll
            for (int db = 0; db < 4; ++db)
                o[t][db] = __builtin_amdgcn_mfma_f32_16x16x32_bf16(ap.v, bv8[db], o[t][db], 0, 0, 0);
            __builtin_amdgcn_s_setprio(0);
        }
        __builtin_amdgcn_sched_barrier(0);
    }
#undef STAGE

    // ---- epilogue: l over quads (shfl); O/l over kh pairs via LDS; write bf16.
    __syncthreads();
    #pragma unroll
    for (int t = 0; t < 2; ++t) {
        float v = lp[t];
        v += __shfl_xor(v, 16, 64);
        v += __shfl_xor(v, 32, 64);
        if (quad == 0) Lred[(wave * 2 + t) * 16 + l15] = v;
    }
    __syncthreads();
    float* myO = Ored + wave * (16 * 64);
    #pragma unroll
    for (int t = 0; t < 2; ++t) {
        #pragma unroll
        for (int db = 0; db < 4; ++db)
            #pragma unroll
            for (int r = 0; r < 4; ++r)
                myO[(quad * 4 + r) * 64 + db * 16 + l15] = o[t][db][r];
        __syncthreads();
        {
            int q_l = tid >> 3;              // 0..31
            int dg = tid & 7;
            int qh2 = q_l >> 4, qq = q_l & 15;
            const float* r0p = Ored + (qh2 * 2 + 0) * (16 * 64) + qq * 64 + dg * 8;
            const float* r1p = Ored + (qh2 * 2 + 1) * (16 * 64) + qq * 64 + dg * 8;
            float4 a0 = *(const float4*)&r0p[0];
            float4 a1 = *(const float4*)&r0p[4];
            float4 c0 = *(const float4*)&r1p[0];
            float4 c1 = *(const float4*)&r1p[4];
            float lt = Lred[((qh2 * 2 + 0) * 2 + t) * 16 + qq] +
                       Lred[((qh2 * 2 + 1) * 2 + t) * 16 + qq];
            float inv = 1.f / lt;
            size_t row = qrow0 + qh2 * 32 + t * 16 + qq;
            unsigned short* dst = &Ab[row * EMB + h * 64 + dg * 8];
            ushort4 lo = { f_to_bf16((a0.x + c0.x) * inv), f_to_bf16((a0.y + c0.y) * inv),
                           f_to_bf16((a0.z + c0.z) * inv), f_to_bf16((a0.w + c0.w) * inv) };
            ushort4 hi = { f_to_bf16((a1.x + c1.x) * inv), f_to_bf16((a1.y + c1.y) * inv),
                           f_to_bf16((a1.z + c1.z) * inv), f_to_bf16((a1.w + c1.w) * inv) };
            *(ushort4*)&dst[0] = lo;
            *(ushort4*)&dst[4] = hi;
        }
        __syncthreads();
    }
}

// ---- y = x + P; LayerNorm -> out. 4 rows per block (1 wave each).
__global__ __launch_bounds__(256) void ln_kernel(
        const float* __restrict__ xf, const unsigned short* __restrict__ xraw,
        const unsigned short* __restrict__ P,
        const float* __restrict__ gamma, const float* __restrict__ beta,
        void* __restrict__ out) {
    int fp32 = detect_fp32(xraw);
    int row = blockIdx.x * 4 + (threadIdx.x >> 6);
    int t = threadIdx.x & 63;
    float v[8];
    float s = 0.f, ss = 0.f;
    const unsigned short* pp = &P[(size_t)row * EMB + t * 8];
    ushort4 p0 = *(const ushort4*)&pp[0];
    ushort4 p1 = *(const ushort4*)&pp[4];
    float pv[8] = { bf16_to_f(p0.x), bf16_to_f(p0.y), bf16_to_f(p0.z), bf16_to_f(p0.w),
                    bf16_to_f(p1.x), bf16_to_f(p1.y), bf16_to_f(p1.z), bf16_to_f(p1.w) };
    if (fp32) {
        const float* xp = &xf[(size_t)row * EMB + t * 8];
        for (int i = 0; i < 8; i += 4) {
            float4 x4 = *(const float4*)&xp[i];
            v[i] = x4.x + pv[i]; v[i+1] = x4.y + pv[i+1];
            v[i+2] = x4.z + pv[i+2]; v[i+3] = x4.w + pv[i+3];
        }
    } else {
        const unsigned short* xp = &xraw[(size_t)row * EMB + t * 8];
        ushort4 x0 = *(const ushort4*)&xp[0];
        ushort4 x1 = *(const ushort4*)&xp[4];
        v[0] = bf16_to_f(x0.x) + pv[0]; v[1] = bf16_to_f(x0.y) + pv[1];
        v[2] = bf16_to_f(x0.z) + pv[2]; v[3] = bf16_to_f(x0.w) + pv[3];
        v[4] = bf16_to_f(x1.x) + pv[4]; v[5] = bf16_to_f(x1.y) + pv[5];
        v[6] = bf16_to_f(x1.z) + pv[6]; v[7] = bf16_to_f(x1.w) + pv[7];
    }
    for (int i = 0; i < 8; ++i) { s += v[i]; ss += v[i] * v[i]; }
    for (int off = 32; off > 0; off >>= 1) {
        s  += __shfl_xor(s, off, 64);
        ss += __shfl_xor(ss, off, 64);
    }
    float mu = s * (1.f / 512.f);
    float var = ss * (1.f / 512.f) - mu * mu;
    float rs = rsqrtf(var + 1e-5f);
    for (int i = 0; i < 8; ++i) {
        int col = t * 8 + i;
        float y = (v[i] - mu) * rs * gamma[col] + beta[col];
        if (fp32) ((float*)out)[(size_t)row * EMB + col] = y;
        else      ((__hip_bfloat16*)out)[(size_t)row * EMB + col] = __float2bfloat16(y);
    }
}

extern "C" void kernel_launch(void* const* d_in, const int* in_sizes, int n_in,
                              void* d_out, int out_size, void* d_ws, size_t ws_size,
                              hipStream_t stream) {
    char* ws = (char*)d_ws;
    char* p = ws + 256;
    float* bias_all = (float*)p;       p += 6 * 512 * 4;
    unsigned short* Wt   = (unsigned short*)p; p += (size_t)2048 * 512 * 2;  // 2MB
    unsigned short* QKVb = (unsigned short*)p; p += (size_t)ROWS * 1536 * 2; // 24MB
    unsigned short* Vt   = (unsigned short*)p; p += (size_t)16 * HD * SEQ * 2; // 8MB
    // shared region: xb (prep -> QKV gemm) then Ab (attn -> O-proj)
    unsigned short* xb = (unsigned short*)p;
    unsigned short* Ab = (unsigned short*)p;   p += (size_t)ROWS * EMB * 2;  // 8MB
    unsigned short* Pb = (unsigned short*)p;   p += (size_t)ROWS * EMB * 2;  // 8MB

    prep_kernel<<<4364, 256, 0, stream>>>(d_in[0], xb,
        d_in[1], d_in[3], d_in[5], d_in[7], Wt,
        d_in[2], d_in[4], d_in[6], d_in[8], d_in[9], d_in[10], bias_all);

    // fused QKV: N=1536; Q cols pre-scaled by QSCALE; V cols written transposed to Vt
    gemm_mfma_kernel<unsigned short><<<dim3(12, 64), 256, 0, stream>>>(
        xb, (const unsigned short*)d_in[0], Wt, bias_all, QKVb, 1536, 512, Vt);

    attn_kernel<<<dim3(1024), 256, 0, stream>>>(QKVb, Vt, Ab);

    // O-proj -> bf16
    gemm_mfma_kernel<unsigned short><<<dim3(4, 64), 256, 0, stream>>>(
        Ab, Ab, Wt + (size_t)1536 * 512, bias_all + 1536, Pb, 512, 0,
        (unsigned short*)nullptr);

    ln_kernel<<<ROWS / 4, 256, 0, stream>>>((const float*)d_in[0],
                                            (const unsigned short*)d_in[0], Pb,
                                            bias_all + 4 * 512, bias_all + 5 * 512, d_out);
}

// Round 8
// 213.286 us; speedup vs baseline: 1.0379x; 1.0379x over previous
//
#include <hip/hip_runtime.h>
#include <hip/hip_bf16.h>

// SelfAttention B=2,N=4096,E=512,H=8,D=64 — Round 18:
// R17 post-mortem: epilogue coalescing neutral -> non-attn time is mostly
// fixed harness overhead + small kernels; attn (84us) is the main addressable
// chunk. R18: (a) attn l-sum moved VALU->MFMA pipe via all-ones B-frag
// (removes 14 VALU adds/kt + shfl epilogue; l now consistent with bf16 P
// numerator). (b) O-proj + LN fused: block = 32 rows x 512 cols, A LDS-staged
// once, barrier-free K-loop, B-frags direct from L2-resident Wo, P-tile in
// LDS, per-wave LN. 4 dispatches total.

#define ROWS 8192
#define EMB  512
#define SEQ  4096
#define HEADS 8
#define HD   64
#define QSCALE 0.18033688011112042f   // 0.125 * log2(e)

typedef __attribute__((ext_vector_type(8))) short bf16x8;
typedef __attribute__((ext_vector_type(4))) short bf16x4;
typedef __attribute__((ext_vector_type(4))) float f32x4;

__device__ __forceinline__ float bf16_to_f(unsigned short u) {
    union { unsigned int i; float f; } v; v.i = ((unsigned int)u) << 16; return v.f;
}
__device__ __forceinline__ unsigned short f_to_bf16(float f) {
    union { __hip_bfloat16 h; unsigned short u; } v; v.h = __float2bfloat16(f); return v.u;
}
// low16 = hi16(a), high16 = hi16(b) — single v_perm_b32
__device__ __forceinline__ unsigned int pack_bf16_trunc(float a, float b) {
    return __builtin_amdgcn_perm(__float_as_uint(b), __float_as_uint(a), 0x07060302u);
}
__device__ __forceinline__ void load_lds16(const void* g, void* l) {
    __builtin_amdgcn_global_load_lds(
        (const __attribute__((address_space(1))) void*)g,
        (__attribute__((address_space(3))) void*)l, 16, 0, 0);
}

// ---- inline dtype detection: fp32 buffers have wild "exponents" in halfwords.
__device__ __forceinline__ int detect_fp32(const void* x) {
    const unsigned short* p = (const unsigned short*)x;
    int t = threadIdx.x & 63;
    int cnt = 0;
    #pragma unroll
    for (int i = 0; i < 4; ++i) {
        unsigned short u = p[t * 4 + i];
        int e = (u >> 7) & 0xFF;
        cnt += (e >= 140) ? 1 : 0;
    }
    #pragma unroll
    for (int off = 32; off > 0; off >>= 1) cnt += __shfl_xor(cnt, off, 64);
    return cnt > 16;
}

// ---- fused prep: [0,4096) conv_x | [4096,4352) conv_wt | [4352,4364) conv_small
__global__ __launch_bounds__(256) void prep_kernel(
        const void* __restrict__ x, unsigned short* __restrict__ xb,
        const void* W0, const void* W1, const void* W2, const void* W3,
        unsigned short* __restrict__ Wt,
        const void* b0, const void* b1, const void* b2, const void* b3,
        const void* b4, const void* b5, float* __restrict__ bias_all) {
    int fp32 = detect_fp32(x);
    int bid = blockIdx.x;
    int tid = threadIdx.x;
    if (bid < 4096) {                       // ---- conv_x: x -> xb (bf16)
        if (!fp32) return;
        int i = (bid * 256 + tid) * 4;
        float4 v = *(const float4*)((const float*)x + i);
        ushort4 u = { f_to_bf16(v.x), f_to_bf16(v.y), f_to_bf16(v.z), f_to_bf16(v.w) };
        *(ushort4*)(xb + i) = u;
    } else if (bid < 4352) {                // ---- conv_wt: W[K][N] -> Wt[n][k]
        __shared__ float T[64][65];
        int idx0 = bid - 4096;
        int kt = idx0 & 7, nt = (idx0 >> 3) & 7, mat = idx0 >> 6;
        const void* src = (mat == 0) ? W0 : (mat == 1) ? W1 : (mat == 2) ? W2 : W3;
        for (int ii = 0; ii < 4; ++ii) {
            int idx = tid + ii * 256;
            int i = idx >> 4, j = (idx & 15) * 4;
            size_t g = (size_t)(kt * 64 + i) * 512 + nt * 64 + j;
            if (fp32) {
                float4 v = *(const float4*)((const float*)src + g);
                T[i][j] = v.x; T[i][j+1] = v.y; T[i][j+2] = v.z; T[i][j+3] = v.w;
            } else {
                ushort4 u = *(const ushort4*)((const unsigned short*)src + g);
                T[i][j] = bf16_to_f(u.x); T[i][j+1] = bf16_to_f(u.y);
                T[i][j+2] = bf16_to_f(u.z); T[i][j+3] = bf16_to_f(u.w);
            }
        }
        __syncthreads();
        for (int ii = 0; ii < 2; ++ii) {
            int idx = tid + ii * 256;
            int j = idx >> 3, ch = idx & 7;
            unsigned short pk[8];
            for (int t = 0; t < 8; ++t) pk[t] = f_to_bf16(T[ch * 8 + t][j]);
            *(bf16x8*)&Wt[(size_t)(mat * 512 + nt * 64 + j) * 512 + kt * 64 + ch * 8] = *(bf16x8*)pk;
        }
    } else {                                // ---- conv_small: 6 vecs -> bias_all
        int idx = (bid - 4352) * 256 + tid;
        int mat = idx >> 9, off = idx & 511;
        const void* src = (mat == 0) ? b0 : (mat == 1) ? b1 : (mat == 2) ? b2 :
                          (mat == 3) ? b3 : (mat == 4) ? b4 : b5;
        float v;
        if (fp32) v = ((const float*)src)[off];
        else      v = bf16_to_f(((const unsigned short*)src)[off]);
        bias_all[idx] = v;
    }
}

// ---- MFMA GEMM (QKV only now): C = A * Bt^T + bias, 128x128x64 tiles,
// 2-phase double-buffered. Epilogue: LDS re-tile -> coalesced stores.
// C-blocks use swapped mfma(b,a); V-blocks (VtOut && n0>=1024) classic order.
template <typename OutT>
__global__ __launch_bounds__(256) void gemm_mfma_kernel(
        const unsigned short* __restrict__ A_conv, const unsigned short* __restrict__ A_raw,
        const unsigned short* __restrict__ Bt,
        const float* __restrict__ bias, OutT* __restrict__ C, int ldc, int scale_cols,
        unsigned short* __restrict__ VtOut) {
    __shared__ __align__(16) unsigned short smemg[2][2][128 * 64];  // [buf][A/B] 64KB
    const unsigned short* A = detect_fp32(A_raw) ? A_conv : A_raw;
    int tid = threadIdx.x;
    int wave = tid >> 6, lane = tid & 63;
    int l15 = lane & 15, quad = lane >> 4;

    int lin = blockIdx.x + gridDim.x * blockIdx.y;
    int nwg = gridDim.x * gridDim.y;
    int bx, by;
    if (nwg & 7) { bx = blockIdx.x; by = blockIdx.y; }
    else {
        int t = (lin & 7) * (nwg >> 3) + (lin >> 3);
        bx = t % gridDim.x; by = t / gridDim.x;
    }
    int m0 = by * 128, n0 = bx * 128;
    int wm = (wave & 1) * 64, wn = (wave >> 1) * 64;
    bool is_v = (VtOut != nullptr) && (n0 >= 1024);

    int rt = wave * 32 + (lane >> 3);
    int ch = (lane & 7) ^ ((lane >> 3) & 7);
    const unsigned short* ag = A  + (size_t)(m0 + rt) * 512 + ch * 8;
    const unsigned short* bg = Bt + (size_t)(n0 + rt) * 512 + ch * 8;

    f32x4 acc[4][4];
    for (int i = 0; i < 4; ++i) for (int j = 0; j < 4; ++j) acc[i][j] = (f32x4){0.f,0.f,0.f,0.f};

#define GSTAGE(buf, k0) do {                                                      \
        unsigned short* Atb = &smemg[buf][0][0];                                  \
        unsigned short* Bsb = &smemg[buf][1][0];                                  \
        _Pragma("unroll")                                                         \
        for (int j = 0; j < 4; ++j) {                                             \
            load_lds16(ag + (size_t)(j * 8) * 512 + (k0), &Atb[(wave * 32 + j * 8) * 64]); \
            load_lds16(bg + (size_t)(j * 8) * 512 + (k0), &Bsb[(wave * 32 + j * 8) * 64]); \
        }                                                                         \
    } while (0)

    GSTAGE(0, 0);   // prologue

    for (int s = 0; s < 8; ++s) {
        int cur = s & 1;
        asm volatile("s_waitcnt vmcnt(0)" ::: "memory");
        __builtin_amdgcn_sched_barrier(0);
        asm volatile("s_barrier" ::: "memory");
        __builtin_amdgcn_sched_barrier(0);
        if (s + 1 < 8) GSTAGE(cur ^ 1, (s + 1) * 64);   // in flight during compute

        const unsigned short* At = &smemg[cur][0][0];
        const unsigned short* Bs = &smemg[cur][1][0];
        #pragma unroll
        for (int ks = 0; ks < 2; ++ks) {
            bf16x8 a[4], b[4];
            #pragma unroll
            for (int f = 0; f < 4; ++f) {
                int pc = ((ks * 4 + quad) ^ (l15 & 7)) * 8;
                a[f] = *(const bf16x8*)&At[(wm + f * 16 + l15) * 64 + pc];
                b[f] = *(const bf16x8*)&Bs[(wn + f * 16 + l15) * 64 + pc];
            }
            if (is_v) {
                #pragma unroll
                for (int fm = 0; fm < 4; ++fm)
                    #pragma unroll
                    for (int fn = 0; fn < 4; ++fn)
                        acc[fm][fn] = __builtin_amdgcn_mfma_f32_16x16x32_bf16(a[fm], b[fn], acc[fm][fn], 0, 0, 0);
            } else {
                #pragma unroll
                for (int fm = 0; fm < 4; ++fm)
                    #pragma unroll
                    for (int fn = 0; fn < 4; ++fn)
                        acc[fm][fn] = __builtin_amdgcn_mfma_f32_16x16x32_bf16(b[fn], a[fm], acc[fm][fn], 0, 0, 0);
            }
        }
        __builtin_amdgcn_sched_barrier(0);
    }
#undef GSTAGE

    // ---- epilogue: LDS re-tile (32KB, aliases dbuf) -> coalesced stores
    __syncthreads();
    unsigned short* LT = &smemg[0][0][0];   // [128 rows][128 ushorts], 8B-chunk swizzle

    float sc = (n0 < scale_cols) ? QSCALE : 1.f;

    if (is_v) {
        #pragma unroll
        for (int fm = 0; fm < 4; ++fm) {
            #pragma unroll
            for (int fn = 0; fn < 4; ++fn) {
                int dcol = wn + fn * 16 + l15;
                float bia = bias[n0 + dcol];
                int seq0 = wm + fm * 16 + quad * 4;
                ushort4 pk = { f_to_bf16(acc[fm][fn][0] + bia),
                               f_to_bf16(acc[fm][fn][1] + bia),
                               f_to_bf16(acc[fm][fn][2] + bia),
                               f_to_bf16(acc[fm][fn][3] + bia) };
                int c8 = (seq0 >> 2) ^ (dcol & 31);
                *(ushort4*)&LT[dcol * 128 + c8 * 4] = pk;
            }
        }
    } else {
        #pragma unroll
        for (int fm = 0; fm < 4; ++fm) {
            #pragma unroll
            for (int fn = 0; fn < 4; ++fn) {
                int row = wm + fm * 16 + l15;
                int col0 = wn + fn * 16 + quad * 4;
                float4 b4 = *(const float4*)&bias[n0 + col0];
                ushort4 pk = { f_to_bf16((acc[fm][fn][0] + b4.x) * sc),
                               f_to_bf16((acc[fm][fn][1] + b4.y) * sc),
                               f_to_bf16((acc[fm][fn][2] + b4.z) * sc),
                               f_to_bf16((acc[fm][fn][3] + b4.w) * sc) };
                int c8 = (col0 >> 2) ^ (row & 31);
                *(ushort4*)&LT[row * 128 + c8 * 4] = pk;
            }
        }
    }
    __syncthreads();
    #pragma unroll
    for (int i = 0; i < 16; ++i) {
        int row = wave * 32 + i * 2 + (lane >> 5);
        int c8 = lane & 31;
        int phys = c8 ^ (row & 31);
        ushort4 v4 = *(const ushort4*)&LT[row * 128 + phys * 4];
        if (is_v) {
            int hd = n0 - 1024 + row;
            int bh = (m0 >> 12) * 8 + (hd >> 6);
            int d  = hd & 63;
            *(ushort4*)&VtOut[((size_t)(bh * 64 + d)) * SEQ + (m0 & 4095) + c8 * 4] = v4;
        } else {
            *(ushort4*)&C[(size_t)(m0 + row) * ldc + n0 + c8 * 4] = v4;
        }
    }
}

// ---- MFMA flash attention, 2-phase double-buffered, K32 PV.
// R18: l-sum via all-ones B-frag MFMA (ol[t]) instead of VALU adds + shfl.
__global__ __launch_bounds__(256, 4) void attn_kernel(
        const unsigned short* __restrict__ QKV, const unsigned short* __restrict__ Vt,
        unsigned short* __restrict__ Ab) {
    __shared__ __align__(16) unsigned char smem[32768];
    float* Ored = (float*)smem;                 // epilogue [4 w][16 q][64 d] (16KB)
    float* Lred = (float*)(smem + 16384);       // epilogue [4 w][2 t][16 q] (512B)

    int tid = threadIdx.x;
    int wave = tid >> 6, lane = tid & 63;
    int l15 = lane & 15, quad = lane >> 4;
    int qh = wave >> 1, kh = wave & 1;
    int lin = blockIdx.x;
    int xcd = lin & 7, slot = lin >> 3;
    int grp = xcd + 8 * (slot >> 6);      // 16 (b,h) groups, 2 per XCD
    int qt = slot & 63;
    int h = grp & 7, b = grp >> 3;
    int bh = b * HEADS + h;
    size_t qrow0 = (size_t)b * SEQ + qt * 64;

    bf16x8 aq[2][2];
    #pragma unroll
    for (int t = 0; t < 2; ++t) {
        const unsigned short* qp = &QKV[(qrow0 + qh * 32 + t * 16 + l15) * 1536 + h * 64];
        aq[t][0] = *(const bf16x8*)&qp[quad * 8];
        aq[t][1] = *(const bf16x8*)&qp[32 + quad * 8];
    }
    f32x4 o[2][4];
    #pragma unroll
    for (int t = 0; t < 2; ++t)
        #pragma unroll
        for (int db = 0; db < 4; ++db) o[t][db] = (f32x4){0.f, 0.f, 0.f, 0.f};
    f32x4 ol[2];   // l accumulator: D[q][*] = sum_k P[q][k] (all cols equal)
    ol[0] = (f32x4){0.f, 0.f, 0.f, 0.f};
    ol[1] = (f32x4){0.f, 0.f, 0.f, 0.f};
    const bf16x8 ones8 = { (short)0x3F80, (short)0x3F80, (short)0x3F80, (short)0x3F80,
                           (short)0x3F80, (short)0x3F80, (short)0x3F80, (short)0x3F80 };

    int r8 = lane >> 3;
    int kch = (lane & 7) ^ (r8 & 7);
    int r0 = wave * 16 + r8;
    int r1 = wave * 16 + 8 + r8;
    int p0r = (r0 & 32) | (((r0 >> 2) & 3) << 3) | (((r0 >> 4) & 1) << 2) | (r0 & 3);
    int p1r = (r1 & 32) | (((r1 >> 2) & 3) << 3) | (((r1 >> 4) & 1) << 2) | (r1 & 3);
    const unsigned short* kg0 = &QKV[((size_t)b * SEQ + p0r) * 1536 + 512 + h * 64 + kch * 8];
    const unsigned short* kg1 = &QKV[((size_t)b * SEQ + p1r) * 1536 + 512 + h * 64 + kch * 8];
    const unsigned short* vg = &Vt[((size_t)bh * 64 + wave * 16 + r8) * SEQ + kch * 8];

#define STAGE(buf, kt2) do {                                                          \
        unsigned short* Ksb = (unsigned short*)(smem + (buf) * 8192);                 \
        unsigned short* Vsb = (unsigned short*)(smem + 16384 + (buf) * 8192);         \
        load_lds16(kg0 + (size_t)((kt2) * 64) * 1536, &Ksb[(wave * 16) * 64]);        \
        load_lds16(kg1 + (size_t)((kt2) * 64) * 1536, &Ksb[(wave * 16 + 8) * 64]);    \
        load_lds16(vg + (size_t)((kt2) * 64), &Vsb[(wave * 16) * 64]);                \
        load_lds16(vg + (size_t)((kt2) * 64) + (size_t)8 * SEQ,                       \
                   &Vsb[(wave * 16 + 8) * 64]);                                       \
    } while (0)

    STAGE(0, 0);   // prologue

    for (int kt = 0; kt < SEQ / 64; ++kt) {
        int cur = kt & 1;
        asm volatile("s_waitcnt vmcnt(0)" ::: "memory");
        __builtin_amdgcn_sched_barrier(0);
        asm volatile("s_barrier" ::: "memory");
        __builtin_amdgcn_sched_barrier(0);
        if (kt + 1 < SEQ / 64) STAGE(cur ^ 1, kt + 1);

        const unsigned short* Ksc = (const unsigned short*)(smem + cur * 8192);
        const unsigned short* Vsc = (const unsigned short*)(smem + 16384 + cur * 8192);

        bf16x8 kA[2][2];
        #pragma unroll
        for (int nb = 0; nb < 2; ++nb) {
            int krow = kh * 32 + nb * 16 + l15;
            int key = krow & 7;
            kA[nb][0] = *(const bf16x8*)&Ksc[krow * 64 + (quad ^ key) * 8];
            kA[nb][1] = *(const bf16x8*)&Ksc[krow * 64 + ((4 + quad) ^ key) * 8];
        }
        bf16x8 bv8[4];
        #pragma unroll
        for (int db = 0; db < 4; ++db) {
            int d = db * 16 + l15;
            bv8[db] = *(const bf16x8*)&Vsc[d * 64 + (((kh * 4 + quad) ^ (d & 7))) * 8];
        }
        #pragma unroll
        for (int t = 0; t < 2; ++t) {
            f32x4 sv0 = {0.f, 0.f, 0.f, 0.f};
            f32x4 sv1 = {0.f, 0.f, 0.f, 0.f};
            __builtin_amdgcn_s_setprio(1);
            sv0 = __builtin_amdgcn_mfma_f32_16x16x32_bf16(kA[0][0], aq[t][0], sv0, 0, 0, 0);
            sv0 = __builtin_amdgcn_mfma_f32_16x16x32_bf16(kA[0][1], aq[t][1], sv0, 0, 0, 0);
            sv1 = __builtin_amdgcn_mfma_f32_16x16x32_bf16(kA[1][0], aq[t][0], sv1, 0, 0, 0);
            sv1 = __builtin_amdgcn_mfma_f32_16x16x32_bf16(kA[1][1], aq[t][1], sv1, 0, 0, 0);
            __builtin_amdgcn_s_setprio(0);
            float p0 = __builtin_amdgcn_exp2f(sv0[0]);
            float p1 = __builtin_amdgcn_exp2f(sv0[1]);
            float p2 = __builtin_amdgcn_exp2f(sv0[2]);
            float p3 = __builtin_amdgcn_exp2f(sv0[3]);
            float p4 = __builtin_amdgcn_exp2f(sv1[0]);
            float p5 = __builtin_amdgcn_exp2f(sv1[1]);
            float p6 = __builtin_amdgcn_exp2f(sv1[2]);
            float p7 = __builtin_amdgcn_exp2f(sv1[3]);
            union { unsigned int u[4]; bf16x8 v; } ap;
            ap.u[0] = pack_bf16_trunc(p0, p1);
            ap.u[1] = pack_bf16_trunc(p2, p3);
            ap.u[2] = pack_bf16_trunc(p4, p5);
            ap.u[3] = pack_bf16_trunc(p6, p7);
            __builtin_amdgcn_s_setprio(1);
            #pragma unroll
            for (int db = 0; db < 4; ++db)
                o[t][db] = __builtin_amdgcn_mfma_f32_16x16x32_bf16(ap.v, bv8[db], o[t][db], 0, 0, 0);
            ol[t] = __builtin_amdgcn_mfma_f32_16x16x32_bf16(ap.v, ones8, ol[t], 0, 0, 0);
            __builtin_amdgcn_s_setprio(0);
        }
        __builtin_amdgcn_sched_barrier(0);
    }
#undef STAGE

    // ---- epilogue: l from ol regs (q = quad*4+r, uniform over l15);
    // O/l over kh pairs via LDS; write bf16.
    __syncthreads();   // all waves done reading Vs (Lred aliases it)
    if (l15 == 0) {
        #pragma unroll
        for (int t = 0; t < 2; ++t)
            #pragma unroll
            for (int r = 0; r < 4; ++r)
                Lred[(wave * 2 + t) * 16 + quad * 4 + r] = ol[t][r];
    }
    __syncthreads();
    float* myO = Ored + wave * (16 * 64);
    #pragma unroll
    for (int t = 0; t < 2; ++t) {
        #pragma unroll
        for (int db = 0; db < 4; ++db)
            #pragma unroll
            for (int r = 0; r < 4; ++r)
                myO[(quad * 4 + r) * 64 + db * 16 + l15] = o[t][db][r];
        __syncthreads();
        {
            int q_l = tid >> 3;              // 0..31
            int dg = tid & 7;
            int qh2 = q_l >> 4, qq = q_l & 15;
            const float* r0p = Ored + (qh2 * 2 + 0) * (16 * 64) + qq * 64 + dg * 8;
            const float* r1p = Ored + (qh2 * 2 + 1) * (16 * 64) + qq * 64 + dg * 8;
            float4 a0 = *(const float4*)&r0p[0];
            float4 a1 = *(const float4*)&r0p[4];
            float4 c0 = *(const float4*)&r1p[0];
            float4 c1 = *(const float4*)&r1p[4];
            float lt = Lred[((qh2 * 2 + 0) * 2 + t) * 16 + qq] +
                       Lred[((qh2 * 2 + 1) * 2 + t) * 16 + qq];
            float inv = 1.f / lt;
            size_t row = qrow0 + qh2 * 32 + t * 16 + qq;
            unsigned short* dst = &Ab[row * EMB + h * 64 + dg * 8];
            ushort4 lo = { f_to_bf16((a0.x + c0.x) * inv), f_to_bf16((a0.y + c0.y) * inv),
                           f_to_bf16((a0.z + c0.z) * inv), f_to_bf16((a0.w + c0.w) * inv) };
            ushort4 hi = { f_to_bf16((a1.x + c1.x) * inv), f_to_bf16((a1.y + c1.y) * inv),
                           f_to_bf16((a1.z + c1.z) * inv), f_to_bf16((a1.w + c1.w) * inv) };
            *(ushort4*)&dst[0] = lo;
            *(ushort4*)&dst[4] = hi;
        }
        __syncthreads();
    }
}

// ---- Fused O-proj + residual + LayerNorm. Block = 32 rows x full 512 cols.
// A (Ab) staged to LDS once (swizzled); barrier-free K-loop with B-frags
// loaded directly from L2-resident Wo[n][k]; P-tile written into the dead
// A-LDS; then per-wave LN (8 rows each) and store.
__global__ __launch_bounds__(256) void oproj_ln_kernel(
        const unsigned short* __restrict__ Ab, const unsigned short* __restrict__ Wo,
        const float* __restrict__ bias_all,
        const float* __restrict__ xf, const unsigned short* __restrict__ xraw,
        void* __restrict__ out) {
    __shared__ __align__(16) unsigned short Aslds[32 * 512];   // 32KB; later = P-tile
    int fp32 = detect_fp32(xraw);
    int tid = threadIdx.x;
    int wave = tid >> 6, lane = tid & 63;
    int l15 = lane & 15, quad = lane >> 4;
    int m0 = blockIdx.x * 32;

    // stage A rows m0..m0+31: LDS[row][c] <- A[row][c ^ (row&7)] (16B chunks)
    {
        int c = lane;
        #pragma unroll
        for (int j = 0; j < 8; ++j) {
            int row = j * 4 + wave;
            int csrc = c ^ (row & 7);
            load_lds16(&Ab[(size_t)(m0 + row) * 512 + csrc * 8],
                       &Aslds[row * 512 + c * 8]);
        }
    }
    asm volatile("s_waitcnt vmcnt(0)" ::: "memory");
    __syncthreads();

    // K-loop: wave w owns cols w*128..+128, all 32 rows.
    f32x4 acc[2][8];
    #pragma unroll
    for (int mf = 0; mf < 2; ++mf)
        #pragma unroll
        for (int nf = 0; nf < 8; ++nf) acc[mf][nf] = (f32x4){0.f, 0.f, 0.f, 0.f};

    const unsigned short* bgl = Wo + (size_t)(wave * 128 + l15) * 512 + quad * 8;

    #pragma unroll
    for (int s = 0; s < 8; ++s) {
        bf16x8 b[2][8];
        #pragma unroll
        for (int ks = 0; ks < 2; ++ks)
            #pragma unroll
            for (int nf = 0; nf < 8; ++nf)
                b[ks][nf] = *(const bf16x8*)&bgl[(size_t)nf * (16 * 512) + s * 64 + ks * 32];
        bf16x8 a[2][2];
        #pragma unroll
        for (int ks = 0; ks < 2; ++ks)
            #pragma unroll
            for (int mf = 0; mf < 2; ++mf) {
                int row = mf * 16 + l15;
                int clog = s * 8 + ks * 4 + quad;
                a[ks][mf] = *(const bf16x8*)&Aslds[row * 512 + (clog ^ (row & 7)) * 8];
            }
        #pragma unroll
        for (int ks = 0; ks < 2; ++ks)
            #pragma unroll
            for (int mf = 0; mf < 2; ++mf)
                #pragma unroll
                for (int nf = 0; nf < 8; ++nf)
                    acc[mf][nf] = __builtin_amdgcn_mfma_f32_16x16x32_bf16(a[ks][mf], b[ks][nf], acc[mf][nf], 0, 0, 0);
    }

    // P-tile into LDS (reuse Aslds): row = mf*16 + quad*4 + r, col = wave*128 + nf*16 + l15
    __syncthreads();   // everyone done reading A
    #pragma unroll
    for (int mf = 0; mf < 2; ++mf)
        #pragma unroll
        for (int nf = 0; nf < 8; ++nf) {
            int col = wave * 128 + nf * 16 + l15;
            float bo = bias_all[1536 + col];
            #pragma unroll
            for (int r = 0; r < 4; ++r) {
                int row = mf * 16 + quad * 4 + r;
                Aslds[row * 512 + col] = f_to_bf16(acc[mf][nf][r] + bo);
            }
        }
    __syncthreads();

    // LN: wave w -> rows w*8..w*8+7; lane covers cols lane*8..+8
    const float* gamma = bias_all + 4 * 512;
    const float* beta  = bias_all + 5 * 512;
    float g[8], bt[8];
    #pragma unroll
    for (int i = 0; i < 8; ++i) { g[i] = gamma[lane * 8 + i]; bt[i] = beta[lane * 8 + i]; }

    #pragma unroll
    for (int rr = 0; rr < 8; ++rr) {
        int row = wave * 8 + rr;
        size_t grow = (size_t)(m0 + row);
        const unsigned short* pp = &Aslds[row * 512 + lane * 8];
        ushort4 p0 = *(const ushort4*)&pp[0];
        ushort4 p1 = *(const ushort4*)&pp[4];
        float pv[8] = { bf16_to_f(p0.x), bf16_to_f(p0.y), bf16_to_f(p0.z), bf16_to_f(p0.w),
                        bf16_to_f(p1.x), bf16_to_f(p1.y), bf16_to_f(p1.z), bf16_to_f(p1.w) };
        float v[8];
        if (fp32) {
            const float* xp = &xf[grow * EMB + lane * 8];
            float4 x0 = *(const float4*)&xp[0];
            float4 x1 = *(const float4*)&xp[4];
            v[0] = x0.x + pv[0]; v[1] = x0.y + pv[1]; v[2] = x0.z + pv[2]; v[3] = x0.w + pv[3];
            v[4] = x1.x + pv[4]; v[5] = x1.y + pv[5]; v[6] = x1.z + pv[6]; v[7] = x1.w + pv[7];
        } else {
            const unsigned short* xp = &xraw[grow * EMB + lane * 8];
            ushort4 x0 = *(const ushort4*)&xp[0];
            ushort4 x1 = *(const ushort4*)&xp[4];
            v[0] = bf16_to_f(x0.x) + pv[0]; v[1] = bf16_to_f(x0.y) + pv[1];
            v[2] = bf16_to_f(x0.z) + pv[2]; v[3] = bf16_to_f(x0.w) + pv[3];
            v[4] = bf16_to_f(x1.x) + pv[4]; v[5] = bf16_to_f(x1.y) + pv[5];
            v[6] = bf16_to_f(x1.z) + pv[6]; v[7] = bf16_to_f(x1.w) + pv[7];
        }
        float s = 0.f, ss = 0.f;
        #pragma unroll
        for (int i = 0; i < 8; ++i) { s += v[i]; ss += v[i] * v[i]; }
        #pragma unroll
        for (int off = 32; off > 0; off >>= 1) {
            s  += __shfl_xor(s, off, 64);
            ss += __shfl_xor(ss, off, 64);
        }
        float mu = s * (1.f / 512.f);
        float var = ss * (1.f / 512.f) - mu * mu;
        float rs = rsqrtf(var + 1e-5f);
        if (fp32) {
            float* op = &((float*)out)[grow * EMB + lane * 8];
            float4 o0 = { (v[0] - mu) * rs * g[0] + bt[0], (v[1] - mu) * rs * g[1] + bt[1],
                          (v[2] - mu) * rs * g[2] + bt[2], (v[3] - mu) * rs * g[3] + bt[3] };
            float4 o1 = { (v[4] - mu) * rs * g[4] + bt[4], (v[5] - mu) * rs * g[5] + bt[5],
                          (v[6] - mu) * rs * g[6] + bt[6], (v[7] - mu) * rs * g[7] + bt[7] };
            *(float4*)&op[0] = o0;
            *(float4*)&op[4] = o1;
        } else {
            unsigned short* op = &((unsigned short*)out)[grow * EMB + lane * 8];
            ushort4 o0 = { f_to_bf16((v[0] - mu) * rs * g[0] + bt[0]),
                           f_to_bf16((v[1] - mu) * rs * g[1] + bt[1]),
                           f_to_bf16((v[2] - mu) * rs * g[2] + bt[2]),
                           f_to_bf16((v[3] - mu) * rs * g[3] + bt[3]) };
            ushort4 o1 = { f_to_bf16((v[4] - mu) * rs * g[4] + bt[4]),
                           f_to_bf16((v[5] - mu) * rs * g[5] + bt[5]),
                           f_to_bf16((v[6] - mu) * rs * g[6] + bt[6]),
                           f_to_bf16((v[7] - mu) * rs * g[7] + bt[7]) };
            *(ushort4*)&op[0] = o0;
            *(ushort4*)&op[4] = o1;
        }
    }
}

extern "C" void kernel_launch(void* const* d_in, const int* in_sizes, int n_in,
                              void* d_out, int out_size, void* d_ws, size_t ws_size,
                              hipStream_t stream) {
    char* ws = (char*)d_ws;
    char* p = ws + 256;
    float* bias_all = (float*)p;       p += 6 * 512 * 4;
    unsigned short* Wt   = (unsigned short*)p; p += (size_t)2048 * 512 * 2;  // 2MB
    unsigned short* QKVb = (unsigned short*)p; p += (size_t)ROWS * 1536 * 2; // 24MB
    unsigned short* Vt   = (unsigned short*)p; p += (size_t)16 * HD * SEQ * 2; // 8MB
    // shared region: xb (prep -> QKV gemm) then Ab (attn -> O-proj)
    unsigned short* xb = (unsigned short*)p;
    unsigned short* Ab = (unsigned short*)p;   p += (size_t)ROWS * EMB * 2;  // 8MB

    prep_kernel<<<4364, 256, 0, stream>>>(d_in[0], xb,
        d_in[1], d_in[3], d_in[5], d_in[7], Wt,
        d_in[2], d_in[4], d_in[6], d_in[8], d_in[9], d_in[10], bias_all);

    // fused QKV: N=1536; Q cols pre-scaled by QSCALE; V cols written transposed to Vt
    gemm_mfma_kernel<unsigned short><<<dim3(12, 64), 256, 0, stream>>>(
        xb, (const unsigned short*)d_in[0], Wt, bias_all, QKVb, 1536, 512, Vt);

    attn_kernel<<<dim3(1024), 256, 0, stream>>>(QKVb, Vt, Ab);

    // fused O-proj + residual + LayerNorm
    oproj_ln_kernel<<<ROWS / 32, 256, 0, stream>>>(
        Ab, Wt + (size_t)1536 * 512, bias_all,
        (const float*)d_in[0], (const unsigned short*)d_in[0], d_out);
}

// Round 9
// 203.153 us; speedup vs baseline: 1.0897x; 1.0499x over previous
//
#include <hip/hip_runtime.h>
#include <hip/hip_bf16.h>

// SelfAttention B=2,N=4096,E=512,H=8,D=64 — Round 19:
// R18 post-mortem: attn issue-bound (MfmaUtil 43 + VALUBusy 49 = 93%); the
// per-kt fixed costs (staging, addressing, barriers, 8 b128 kA/bv8 reads) are
// q-count-independent. R19: 128 q per block (grid 512, t=0..3) — fixed costs
// amortize 2x; only exp2/pack/MFMA scale. VGPR ~170 -> launch_bounds(256,2)
// (allocator budget 256, no forced squeeze). 2 blocks/CU resident.

#define ROWS 8192
#define EMB  512
#define SEQ  4096
#define HEADS 8
#define HD   64
#define QSCALE 0.18033688011112042f   // 0.125 * log2(e)

typedef __attribute__((ext_vector_type(8))) short bf16x8;
typedef __attribute__((ext_vector_type(4))) short bf16x4;
typedef __attribute__((ext_vector_type(4))) float f32x4;

__device__ __forceinline__ float bf16_to_f(unsigned short u) {
    union { unsigned int i; float f; } v; v.i = ((unsigned int)u) << 16; return v.f;
}
__device__ __forceinline__ unsigned short f_to_bf16(float f) {
    union { __hip_bfloat16 h; unsigned short u; } v; v.h = __float2bfloat16(f); return v.u;
}
// low16 = hi16(a), high16 = hi16(b) — single v_perm_b32
__device__ __forceinline__ unsigned int pack_bf16_trunc(float a, float b) {
    return __builtin_amdgcn_perm(__float_as_uint(b), __float_as_uint(a), 0x07060302u);
}
__device__ __forceinline__ void load_lds16(const void* g, void* l) {
    __builtin_amdgcn_global_load_lds(
        (const __attribute__((address_space(1))) void*)g,
        (__attribute__((address_space(3))) void*)l, 16, 0, 0);
}

// ---- inline dtype detection: fp32 buffers have wild "exponents" in halfwords.
__device__ __forceinline__ int detect_fp32(const void* x) {
    const unsigned short* p = (const unsigned short*)x;
    int t = threadIdx.x & 63;
    int cnt = 0;
    #pragma unroll
    for (int i = 0; i < 4; ++i) {
        unsigned short u = p[t * 4 + i];
        int e = (u >> 7) & 0xFF;
        cnt += (e >= 140) ? 1 : 0;
    }
    #pragma unroll
    for (int off = 32; off > 0; off >>= 1) cnt += __shfl_xor(cnt, off, 64);
    return cnt > 16;
}

// ---- fused prep: [0,4096) conv_x | [4096,4352) conv_wt | [4352,4364) conv_small
__global__ __launch_bounds__(256) void prep_kernel(
        const void* __restrict__ x, unsigned short* __restrict__ xb,
        const void* W0, const void* W1, const void* W2, const void* W3,
        unsigned short* __restrict__ Wt,
        const void* b0, const void* b1, const void* b2, const void* b3,
        const void* b4, const void* b5, float* __restrict__ bias_all) {
    int fp32 = detect_fp32(x);
    int bid = blockIdx.x;
    int tid = threadIdx.x;
    if (bid < 4096) {                       // ---- conv_x: x -> xb (bf16)
        if (!fp32) return;
        int i = (bid * 256 + tid) * 4;
        float4 v = *(const float4*)((const float*)x + i);
        ushort4 u = { f_to_bf16(v.x), f_to_bf16(v.y), f_to_bf16(v.z), f_to_bf16(v.w) };
        *(ushort4*)(xb + i) = u;
    } else if (bid < 4352) {                // ---- conv_wt: W[K][N] -> Wt[n][k]
        __shared__ float T[64][65];
        int idx0 = bid - 4096;
        int kt = idx0 & 7, nt = (idx0 >> 3) & 7, mat = idx0 >> 6;
        const void* src = (mat == 0) ? W0 : (mat == 1) ? W1 : (mat == 2) ? W2 : W3;
        for (int ii = 0; ii < 4; ++ii) {
            int idx = tid + ii * 256;
            int i = idx >> 4, j = (idx & 15) * 4;
            size_t g = (size_t)(kt * 64 + i) * 512 + nt * 64 + j;
            if (fp32) {
                float4 v = *(const float4*)((const float*)src + g);
                T[i][j] = v.x; T[i][j+1] = v.y; T[i][j+2] = v.z; T[i][j+3] = v.w;
            } else {
                ushort4 u = *(const ushort4*)((const unsigned short*)src + g);
                T[i][j] = bf16_to_f(u.x); T[i][j+1] = bf16_to_f(u.y);
                T[i][j+2] = bf16_to_f(u.z); T[i][j+3] = bf16_to_f(u.w);
            }
        }
        __syncthreads();
        for (int ii = 0; ii < 2; ++ii) {
            int idx = tid + ii * 256;
            int j = idx >> 3, ch = idx & 7;
            unsigned short pk[8];
            for (int t = 0; t < 8; ++t) pk[t] = f_to_bf16(T[ch * 8 + t][j]);
            *(bf16x8*)&Wt[(size_t)(mat * 512 + nt * 64 + j) * 512 + kt * 64 + ch * 8] = *(bf16x8*)pk;
        }
    } else {                                // ---- conv_small: 6 vecs -> bias_all
        int idx = (bid - 4352) * 256 + tid;
        int mat = idx >> 9, off = idx & 511;
        const void* src = (mat == 0) ? b0 : (mat == 1) ? b1 : (mat == 2) ? b2 :
                          (mat == 3) ? b3 : (mat == 4) ? b4 : b5;
        float v;
        if (fp32) v = ((const float*)src)[off];
        else      v = bf16_to_f(((const unsigned short*)src)[off]);
        bias_all[idx] = v;
    }
}

// ---- MFMA GEMM (QKV only): C = A * Bt^T + bias, 128x128x64 tiles,
// 2-phase double-buffered. Epilogue: LDS re-tile -> coalesced stores.
// C-blocks use swapped mfma(b,a); V-blocks (VtOut && n0>=1024) classic order.
template <typename OutT>
__global__ __launch_bounds__(256) void gemm_mfma_kernel(
        const unsigned short* __restrict__ A_conv, const unsigned short* __restrict__ A_raw,
        const unsigned short* __restrict__ Bt,
        const float* __restrict__ bias, OutT* __restrict__ C, int ldc, int scale_cols,
        unsigned short* __restrict__ VtOut) {
    __shared__ __align__(16) unsigned short smemg[2][2][128 * 64];  // [buf][A/B] 64KB
    const unsigned short* A = detect_fp32(A_raw) ? A_conv : A_raw;
    int tid = threadIdx.x;
    int wave = tid >> 6, lane = tid & 63;
    int l15 = lane & 15, quad = lane >> 4;

    int lin = blockIdx.x + gridDim.x * blockIdx.y;
    int nwg = gridDim.x * gridDim.y;
    int bx, by;
    if (nwg & 7) { bx = blockIdx.x; by = blockIdx.y; }
    else {
        int t = (lin & 7) * (nwg >> 3) + (lin >> 3);
        bx = t % gridDim.x; by = t / gridDim.x;
    }
    int m0 = by * 128, n0 = bx * 128;
    int wm = (wave & 1) * 64, wn = (wave >> 1) * 64;
    bool is_v = (VtOut != nullptr) && (n0 >= 1024);

    int rt = wave * 32 + (lane >> 3);
    int ch = (lane & 7) ^ ((lane >> 3) & 7);
    const unsigned short* ag = A  + (size_t)(m0 + rt) * 512 + ch * 8;
    const unsigned short* bg = Bt + (size_t)(n0 + rt) * 512 + ch * 8;

    f32x4 acc[4][4];
    for (int i = 0; i < 4; ++i) for (int j = 0; j < 4; ++j) acc[i][j] = (f32x4){0.f,0.f,0.f,0.f};

#define GSTAGE(buf, k0) do {                                                      \
        unsigned short* Atb = &smemg[buf][0][0];                                  \
        unsigned short* Bsb = &smemg[buf][1][0];                                  \
        _Pragma("unroll")                                                         \
        for (int j = 0; j < 4; ++j) {                                             \
            load_lds16(ag + (size_t)(j * 8) * 512 + (k0), &Atb[(wave * 32 + j * 8) * 64]); \
            load_lds16(bg + (size_t)(j * 8) * 512 + (k0), &Bsb[(wave * 32 + j * 8) * 64]); \
        }                                                                         \
    } while (0)

    GSTAGE(0, 0);   // prologue

    for (int s = 0; s < 8; ++s) {
        int cur = s & 1;
        asm volatile("s_waitcnt vmcnt(0)" ::: "memory");
        __builtin_amdgcn_sched_barrier(0);
        asm volatile("s_barrier" ::: "memory");
        __builtin_amdgcn_sched_barrier(0);
        if (s + 1 < 8) GSTAGE(cur ^ 1, (s + 1) * 64);   // in flight during compute

        const unsigned short* At = &smemg[cur][0][0];
        const unsigned short* Bs = &smemg[cur][1][0];
        #pragma unroll
        for (int ks = 0; ks < 2; ++ks) {
            bf16x8 a[4], b[4];
            #pragma unroll
            for (int f = 0; f < 4; ++f) {
                int pc = ((ks * 4 + quad) ^ (l15 & 7)) * 8;
                a[f] = *(const bf16x8*)&At[(wm + f * 16 + l15) * 64 + pc];
                b[f] = *(const bf16x8*)&Bs[(wn + f * 16 + l15) * 64 + pc];
            }
            if (is_v) {
                #pragma unroll
                for (int fm = 0; fm < 4; ++fm)
                    #pragma unroll
                    for (int fn = 0; fn < 4; ++fn)
                        acc[fm][fn] = __builtin_amdgcn_mfma_f32_16x16x32_bf16(a[fm], b[fn], acc[fm][fn], 0, 0, 0);
            } else {
                #pragma unroll
                for (int fm = 0; fm < 4; ++fm)
                    #pragma unroll
                    for (int fn = 0; fn < 4; ++fn)
                        acc[fm][fn] = __builtin_amdgcn_mfma_f32_16x16x32_bf16(b[fn], a[fm], acc[fm][fn], 0, 0, 0);
            }
        }
        __builtin_amdgcn_sched_barrier(0);
    }
#undef GSTAGE

    // ---- epilogue: LDS re-tile (32KB, aliases dbuf) -> coalesced stores
    __syncthreads();
    unsigned short* LT = &smemg[0][0][0];   // [128 rows][128 ushorts], 8B-chunk swizzle

    float sc = (n0 < scale_cols) ? QSCALE : 1.f;

    if (is_v) {
        #pragma unroll
        for (int fm = 0; fm < 4; ++fm) {
            #pragma unroll
            for (int fn = 0; fn < 4; ++fn) {
                int dcol = wn + fn * 16 + l15;
                float bia = bias[n0 + dcol];
                int seq0 = wm + fm * 16 + quad * 4;
                ushort4 pk = { f_to_bf16(acc[fm][fn][0] + bia),
                               f_to_bf16(acc[fm][fn][1] + bia),
                               f_to_bf16(acc[fm][fn][2] + bia),
                               f_to_bf16(acc[fm][fn][3] + bia) };
                int c8 = (seq0 >> 2) ^ (dcol & 31);
                *(ushort4*)&LT[dcol * 128 + c8 * 4] = pk;
            }
        }
    } else {
        #pragma unroll
        for (int fm = 0; fm < 4; ++fm) {
            #pragma unroll
            for (int fn = 0; fn < 4; ++fn) {
                int row = wm + fm * 16 + l15;
                int col0 = wn + fn * 16 + quad * 4;
                float4 b4 = *(const float4*)&bias[n0 + col0];
                ushort4 pk = { f_to_bf16((acc[fm][fn][0] + b4.x) * sc),
                               f_to_bf16((acc[fm][fn][1] + b4.y) * sc),
                               f_to_bf16((acc[fm][fn][2] + b4.z) * sc),
                               f_to_bf16((acc[fm][fn][3] + b4.w) * sc) };
                int c8 = (col0 >> 2) ^ (row & 31);
                *(ushort4*)&LT[row * 128 + c8 * 4] = pk;
            }
        }
    }
    __syncthreads();
    #pragma unroll
    for (int i = 0; i < 16; ++i) {
        int row = wave * 32 + i * 2 + (lane >> 5);
        int c8 = lane & 31;
        int phys = c8 ^ (row & 31);
        ushort4 v4 = *(const ushort4*)&LT[row * 128 + phys * 4];
        if (is_v) {
            int hd = n0 - 1024 + row;
            int bh = (m0 >> 12) * 8 + (hd >> 6);
            int d  = hd & 63;
            *(ushort4*)&VtOut[((size_t)(bh * 64 + d)) * SEQ + (m0 & 4095) + c8 * 4] = v4;
        } else {
            *(ushort4*)&C[(size_t)(m0 + row) * ldc + n0 + c8 * 4] = v4;
        }
    }
}

// ---- MFMA flash attention, 2-phase double-buffered, K32 PV, l via ones-MFMA.
// R19: 128 q per block (grid 512 = 8 xcd * 64 slots), t = 0..3. Per-kt fixed
// costs (staging, kA/bv8 reads, barriers) amortize over 2x q vs R18.
__global__ __launch_bounds__(256, 2) void attn_kernel(
        const unsigned short* __restrict__ QKV, const unsigned short* __restrict__ Vt,
        unsigned short* __restrict__ Ab) {
    __shared__ __align__(16) unsigned char smem[32768];
    float* Ored = (float*)smem;                 // epilogue [4 w][16 q][64 d] (16KB)
    float* Lred = (float*)(smem + 16384);       // epilogue [4 w][4 t][16 q] (1KB)

    int tid = threadIdx.x;
    int wave = tid >> 6, lane = tid & 63;
    int l15 = lane & 15, quad = lane >> 4;
    int qh = wave >> 1, kh = wave & 1;
    int lin = blockIdx.x;                 // 512 = 8 xcd * 64 slots
    int xcd = lin & 7, slot = lin >> 3;
    int grp = xcd + 8 * (slot >> 5);      // 16 (b,h) groups, 2 per XCD
    int qt = slot & 31;
    int h = grp & 7, b = grp >> 3;
    int bh = b * HEADS + h;
    size_t qrow0 = (size_t)b * SEQ + qt * 128;

    // Q B-frags: rows qh*64 + t*16 + l15, t = 0..3. Pre-scaled by QSCALE.
    bf16x8 aq[4][2];
    #pragma unroll
    for (int t = 0; t < 4; ++t) {
        const unsigned short* qp = &QKV[(qrow0 + qh * 64 + t * 16 + l15) * 1536 + h * 64];
        aq[t][0] = *(const bf16x8*)&qp[quad * 8];
        aq[t][1] = *(const bf16x8*)&qp[32 + quad * 8];
    }
    f32x4 o[4][4];
    #pragma unroll
    for (int t = 0; t < 4; ++t)
        #pragma unroll
        for (int db = 0; db < 4; ++db) o[t][db] = (f32x4){0.f, 0.f, 0.f, 0.f};
    f32x4 ol[4];   // l accumulator: D[q][*] = sum_k P[q][k]
    #pragma unroll
    for (int t = 0; t < 4; ++t) ol[t] = (f32x4){0.f, 0.f, 0.f, 0.f};
    const bf16x8 ones8 = { (short)0x3F80, (short)0x3F80, (short)0x3F80, (short)0x3F80,
                           (short)0x3F80, (short)0x3F80, (short)0x3F80, (short)0x3F80 };

    int r8 = lane >> 3;
    int kch = (lane & 7) ^ (r8 & 7);
    int r0 = wave * 16 + r8;
    int r1 = wave * 16 + 8 + r8;
    int p0r = (r0 & 32) | (((r0 >> 2) & 3) << 3) | (((r0 >> 4) & 1) << 2) | (r0 & 3);
    int p1r = (r1 & 32) | (((r1 >> 2) & 3) << 3) | (((r1 >> 4) & 1) << 2) | (r1 & 3);
    const unsigned short* kg0 = &QKV[((size_t)b * SEQ + p0r) * 1536 + 512 + h * 64 + kch * 8];
    const unsigned short* kg1 = &QKV[((size_t)b * SEQ + p1r) * 1536 + 512 + h * 64 + kch * 8];
    const unsigned short* vg = &Vt[((size_t)bh * 64 + wave * 16 + r8) * SEQ + kch * 8];

#define STAGE(buf, kt2) do {                                                          \
        unsigned short* Ksb = (unsigned short*)(smem + (buf) * 8192);                 \
        unsigned short* Vsb = (unsigned short*)(smem + 16384 + (buf) * 8192);         \
        load_lds16(kg0 + (size_t)((kt2) * 64) * 1536, &Ksb[(wave * 16) * 64]);        \
        load_lds16(kg1 + (size_t)((kt2) * 64) * 1536, &Ksb[(wave * 16 + 8) * 64]);    \
        load_lds16(vg + (size_t)((kt2) * 64), &Vsb[(wave * 16) * 64]);                \
        load_lds16(vg + (size_t)((kt2) * 64) + (size_t)8 * SEQ,                       \
                   &Vsb[(wave * 16 + 8) * 64]);                                       \
    } while (0)

    STAGE(0, 0);   // prologue

    for (int kt = 0; kt < SEQ / 64; ++kt) {
        int cur = kt & 1;
        asm volatile("s_waitcnt vmcnt(0)" ::: "memory");
        __builtin_amdgcn_sched_barrier(0);
        asm volatile("s_barrier" ::: "memory");
        __builtin_amdgcn_sched_barrier(0);
        if (kt + 1 < SEQ / 64) STAGE(cur ^ 1, kt + 1);

        const unsigned short* Ksc = (const unsigned short*)(smem + cur * 8192);
        const unsigned short* Vsc = (const unsigned short*)(smem + 16384 + cur * 8192);

        bf16x8 kA[2][2];
        #pragma unroll
        for (int nb = 0; nb < 2; ++nb) {
            int krow = kh * 32 + nb * 16 + l15;
            int key = krow & 7;
            kA[nb][0] = *(const bf16x8*)&Ksc[krow * 64 + (quad ^ key) * 8];
            kA[nb][1] = *(const bf16x8*)&Ksc[krow * 64 + ((4 + quad) ^ key) * 8];
        }
        bf16x8 bv8[4];
        #pragma unroll
        for (int db = 0; db < 4; ++db) {
            int d = db * 16 + l15;
            bv8[db] = *(const bf16x8*)&Vsc[d * 64 + (((kh * 4 + quad) ^ (d & 7))) * 8];
        }
        #pragma unroll
        for (int t = 0; t < 4; ++t) {
            f32x4 sv0 = {0.f, 0.f, 0.f, 0.f};
            f32x4 sv1 = {0.f, 0.f, 0.f, 0.f};
            __builtin_amdgcn_s_setprio(1);
            sv0 = __builtin_amdgcn_mfma_f32_16x16x32_bf16(kA[0][0], aq[t][0], sv0, 0, 0, 0);
            sv0 = __builtin_amdgcn_mfma_f32_16x16x32_bf16(kA[0][1], aq[t][1], sv0, 0, 0, 0);
            sv1 = __builtin_amdgcn_mfma_f32_16x16x32_bf16(kA[1][0], aq[t][0], sv1, 0, 0, 0);
            sv1 = __builtin_amdgcn_mfma_f32_16x16x32_bf16(kA[1][1], aq[t][1], sv1, 0, 0, 0);
            __builtin_amdgcn_s_setprio(0);
            float p0 = __builtin_amdgcn_exp2f(sv0[0]);
            float p1 = __builtin_amdgcn_exp2f(sv0[1]);
            float p2 = __builtin_amdgcn_exp2f(sv0[2]);
            float p3 = __builtin_amdgcn_exp2f(sv0[3]);
            float p4 = __builtin_amdgcn_exp2f(sv1[0]);
            float p5 = __builtin_amdgcn_exp2f(sv1[1]);
            float p6 = __builtin_amdgcn_exp2f(sv1[2]);
            float p7 = __builtin_amdgcn_exp2f(sv1[3]);
            union { unsigned int u[4]; bf16x8 v; } ap;
            ap.u[0] = pack_bf16_trunc(p0, p1);
            ap.u[1] = pack_bf16_trunc(p2, p3);
            ap.u[2] = pack_bf16_trunc(p4, p5);
            ap.u[3] = pack_bf16_trunc(p6, p7);
            __builtin_amdgcn_s_setprio(1);
            #pragma unroll
            for (int db = 0; db < 4; ++db)
                o[t][db] = __builtin_amdgcn_mfma_f32_16x16x32_bf16(ap.v, bv8[db], o[t][db], 0, 0, 0);
            ol[t] = __builtin_amdgcn_mfma_f32_16x16x32_bf16(ap.v, ones8, ol[t], 0, 0, 0);
            __builtin_amdgcn_s_setprio(0);
        }
        __builtin_amdgcn_sched_barrier(0);
    }
#undef STAGE

    // ---- epilogue: l from ol regs; O/l over kh pairs via LDS; write bf16.
    __syncthreads();   // all waves done reading Vs (Lred aliases it)
    if (l15 == 0) {
        #pragma unroll
        for (int t = 0; t < 4; ++t)
            #pragma unroll
            for (int r = 0; r < 4; ++r)
                Lred[(wave * 4 + t) * 16 + quad * 4 + r] = ol[t][r];
    }
    __syncthreads();
    float* myO = Ored + wave * (16 * 64);
    #pragma unroll
    for (int t = 0; t < 4; ++t) {
        #pragma unroll
        for (int db = 0; db < 4; ++db)
            #pragma unroll
            for (int r = 0; r < 4; ++r)
                myO[(quad * 4 + r) * 64 + db * 16 + l15] = o[t][db][r];
        __syncthreads();
        {
            int q_l = tid >> 3;              // 0..31
            int dg = tid & 7;
            int qh2 = q_l >> 4, qq = q_l & 15;
            const float* r0p = Ored + (qh2 * 2 + 0) * (16 * 64) + qq * 64 + dg * 8;
            const float* r1p = Ored + (qh2 * 2 + 1) * (16 * 64) + qq * 64 + dg * 8;
            float4 a0 = *(const float4*)&r0p[0];
            float4 a1 = *(const float4*)&r0p[4];
            float4 c0 = *(const float4*)&r1p[0];
            float4 c1 = *(const float4*)&r1p[4];
            float lt = Lred[((qh2 * 2 + 0) * 4 + t) * 16 + qq] +
                       Lred[((qh2 * 2 + 1) * 4 + t) * 16 + qq];
            float inv = 1.f / lt;
            size_t row = qrow0 + qh2 * 64 + t * 16 + qq;
            unsigned short* dst = &Ab[row * EMB + h * 64 + dg * 8];
            ushort4 lo = { f_to_bf16((a0.x + c0.x) * inv), f_to_bf16((a0.y + c0.y) * inv),
                           f_to_bf16((a0.z + c0.z) * inv), f_to_bf16((a0.w + c0.w) * inv) };
            ushort4 hi = { f_to_bf16((a1.x + c1.x) * inv), f_to_bf16((a1.y + c1.y) * inv),
                           f_to_bf16((a1.z + c1.z) * inv), f_to_bf16((a1.w + c1.w) * inv) };
            *(ushort4*)&dst[0] = lo;
            *(ushort4*)&dst[4] = hi;
        }
        __syncthreads();
    }
}

// ---- Fused O-proj + residual + LayerNorm (R18, unchanged).
__global__ __launch_bounds__(256) void oproj_ln_kernel(
        const unsigned short* __restrict__ Ab, const unsigned short* __restrict__ Wo,
        const float* __restrict__ bias_all,
        const float* __restrict__ xf, const unsigned short* __restrict__ xraw,
        void* __restrict__ out) {
    __shared__ __align__(16) unsigned short Aslds[32 * 512];   // 32KB; later = P-tile
    int fp32 = detect_fp32(xraw);
    int tid = threadIdx.x;
    int wave = tid >> 6, lane = tid & 63;
    int l15 = lane & 15, quad = lane >> 4;
    int m0 = blockIdx.x * 32;

    {
        int c = lane;
        #pragma unroll
        for (int j = 0; j < 8; ++j) {
            int row = j * 4 + wave;
            int csrc = c ^ (row & 7);
            load_lds16(&Ab[(size_t)(m0 + row) * 512 + csrc * 8],
                       &Aslds[row * 512 + c * 8]);
        }
    }
    asm volatile("s_waitcnt vmcnt(0)" ::: "memory");
    __syncthreads();

    f32x4 acc[2][8];
    #pragma unroll
    for (int mf = 0; mf < 2; ++mf)
        #pragma unroll
        for (int nf = 0; nf < 8; ++nf) acc[mf][nf] = (f32x4){0.f, 0.f, 0.f, 0.f};

    const unsigned short* bgl = Wo + (size_t)(wave * 128 + l15) * 512 + quad * 8;

    #pragma unroll
    for (int s = 0; s < 8; ++s) {
        bf16x8 b[2][8];
        #pragma unroll
        for (int ks = 0; ks < 2; ++ks)
            #pragma unroll
            for (int nf = 0; nf < 8; ++nf)
                b[ks][nf] = *(const bf16x8*)&bgl[(size_t)nf * (16 * 512) + s * 64 + ks * 32];
        bf16x8 a[2][2];
        #pragma unroll
        for (int ks = 0; ks < 2; ++ks)
            #pragma unroll
            for (int mf = 0; mf < 2; ++mf) {
                int row = mf * 16 + l15;
                int clog = s * 8 + ks * 4 + quad;
                a[ks][mf] = *(const bf16x8*)&Aslds[row * 512 + (clog ^ (row & 7)) * 8];
            }
        #pragma unroll
        for (int ks = 0; ks < 2; ++ks)
            #pragma unroll
            for (int mf = 0; mf < 2; ++mf)
                #pragma unroll
                for (int nf = 0; nf < 8; ++nf)
                    acc[mf][nf] = __builtin_amdgcn_mfma_f32_16x16x32_bf16(a[ks][mf], b[ks][nf], acc[mf][nf], 0, 0, 0);
    }

    __syncthreads();   // everyone done reading A
    #pragma unroll
    for (int mf = 0; mf < 2; ++mf)
        #pragma unroll
        for (int nf = 0; nf < 8; ++nf) {
            int col = wave * 128 + nf * 16 + l15;
            float bo = bias_all[1536 + col];
            #pragma unroll
            for (int r = 0; r < 4; ++r) {
                int row = mf * 16 + quad * 4 + r;
                Aslds[row * 512 + col] = f_to_bf16(acc[mf][nf][r] + bo);
            }
        }
    __syncthreads();

    const float* gamma = bias_all + 4 * 512;
    const float* beta  = bias_all + 5 * 512;
    float g[8], bt[8];
    #pragma unroll
    for (int i = 0; i < 8; ++i) { g[i] = gamma[lane * 8 + i]; bt[i] = beta[lane * 8 + i]; }

    #pragma unroll
    for (int rr = 0; rr < 8; ++rr) {
        int row = wave * 8 + rr;
        size_t grow = (size_t)(m0 + row);
        const unsigned short* pp = &Aslds[row * 512 + lane * 8];
        ushort4 p0 = *(const ushort4*)&pp[0];
        ushort4 p1 = *(const ushort4*)&pp[4];
        float pv[8] = { bf16_to_f(p0.x), bf16_to_f(p0.y), bf16_to_f(p0.z), bf16_to_f(p0.w),
                        bf16_to_f(p1.x), bf16_to_f(p1.y), bf16_to_f(p1.z), bf16_to_f(p1.w) };
        float v[8];
        if (fp32) {
            const float* xp = &xf[grow * EMB + lane * 8];
            float4 x0 = *(const float4*)&xp[0];
            float4 x1 = *(const float4*)&xp[4];
            v[0] = x0.x + pv[0]; v[1] = x0.y + pv[1]; v[2] = x0.z + pv[2]; v[3] = x0.w + pv[3];
            v[4] = x1.x + pv[4]; v[5] = x1.y + pv[5]; v[6] = x1.z + pv[6]; v[7] = x1.w + pv[7];
        } else {
            const unsigned short* xp = &xraw[grow * EMB + lane * 8];
            ushort4 x0 = *(const ushort4*)&xp[0];
            ushort4 x1 = *(const ushort4*)&xp[4];
            v[0] = bf16_to_f(x0.x) + pv[0]; v[1] = bf16_to_f(x0.y) + pv[1];
            v[2] = bf16_to_f(x0.z) + pv[2]; v[3] = bf16_to_f(x0.w) + pv[3];
            v[4] = bf16_to_f(x1.x) + pv[4]; v[5] = bf16_to_f(x1.y) + pv[5];
            v[6] = bf16_to_f(x1.z) + pv[6]; v[7] = bf16_to_f(x1.w) + pv[7];
        }
        float s = 0.f, ss = 0.f;
        #pragma unroll
        for (int i = 0; i < 8; ++i) { s += v[i]; ss += v[i] * v[i]; }
        #pragma unroll
        for (int off = 32; off > 0; off >>= 1) {
            s  += __shfl_xor(s, off, 64);
            ss += __shfl_xor(ss, off, 64);
        }
        float mu = s * (1.f / 512.f);
        float var = ss * (1.f / 512.f) - mu * mu;
        float rs = rsqrtf(var + 1e-5f);
        if (fp32) {
            float* op = &((float*)out)[grow * EMB + lane * 8];
            float4 o0 = { (v[0] - mu) * rs * g[0] + bt[0], (v[1] - mu) * rs * g[1] + bt[1],
                          (v[2] - mu) * rs * g[2] + bt[2], (v[3] - mu) * rs * g[3] + bt[3] };
            float4 o1 = { (v[4] - mu) * rs * g[4] + bt[4], (v[5] - mu) * rs * g[5] + bt[5],
                          (v[6] - mu) * rs * g[6] + bt[6], (v[7] - mu) * rs * g[7] + bt[7] };
            *(float4*)&op[0] = o0;
            *(float4*)&op[4] = o1;
        } else {
            unsigned short* op = &((unsigned short*)out)[grow * EMB + lane * 8];
            ushort4 o0 = { f_to_bf16((v[0] - mu) * rs * g[0] + bt[0]),
                           f_to_bf16((v[1] - mu) * rs * g[1] + bt[1]),
                           f_to_bf16((v[2] - mu) * rs * g[2] + bt[2]),
                           f_to_bf16((v[3] - mu) * rs * g[3] + bt[3]) };
            ushort4 o1 = { f_to_bf16((v[4] - mu) * rs * g[4] + bt[4]),
                           f_to_bf16((v[5] - mu) * rs * g[5] + bt[5]),
                           f_to_bf16((v[6] - mu) * rs * g[6] + bt[6]),
                           f_to_bf16((v[7] - mu) * rs * g[7] + bt[7]) };
            *(ushort4*)&op[0] = o0;
            *(ushort4*)&op[4] = o1;
        }
    }
}

extern "C" void kernel_launch(void* const* d_in, const int* in_sizes, int n_in,
                              void* d_out, int out_size, void* d_ws, size_t ws_size,
                              hipStream_t stream) {
    char* ws = (char*)d_ws;
    char* p = ws + 256;
    float* bias_all = (float*)p;       p += 6 * 512 * 4;
    unsigned short* Wt   = (unsigned short*)p; p += (size_t)2048 * 512 * 2;  // 2MB
    unsigned short* QKVb = (unsigned short*)p; p += (size_t)ROWS * 1536 * 2; // 24MB
    unsigned short* Vt   = (unsigned short*)p; p += (size_t)16 * HD * SEQ * 2; // 8MB
    // shared region: xb (prep -> QKV gemm) then Ab (attn -> O-proj)
    unsigned short* xb = (unsigned short*)p;
    unsigned short* Ab = (unsigned short*)p;   p += (size_t)ROWS * EMB * 2;  // 8MB

    prep_kernel<<<4364, 256, 0, stream>>>(d_in[0], xb,
        d_in[1], d_in[3], d_in[5], d_in[7], Wt,
        d_in[2], d_in[4], d_in[6], d_in[8], d_in[9], d_in[10], bias_all);

    // fused QKV: N=1536; Q cols pre-scaled by QSCALE; V cols written transposed to Vt
    gemm_mfma_kernel<unsigned short><<<dim3(12, 64), 256, 0, stream>>>(
        xb, (const unsigned short*)d_in[0], Wt, bias_all, QKVb, 1536, 512, Vt);

    attn_kernel<<<dim3(512), 256, 0, stream>>>(QKVb, Vt, Ab);

    // fused O-proj + residual + LayerNorm
    oproj_ln_kernel<<<ROWS / 32, 256, 0, stream>>>(
        Ab, Wt + (size_t)1536 * 512, bias_all,
        (const float*)d_in[0], (const unsigned short*)d_in[0], d_out);
}